// Round 7
// baseline (406.673 us; speedup 1.0000x reference)
//
#include <hip/hip_runtime.h>

#define BATCH 4096
#define DM 768
#define LTOT 10240
#define NG 124

typedef __bf16 bf16x8 __attribute__((ext_vector_type(8)));
typedef short short8 __attribute__((ext_vector_type(8)));
typedef float f32x4 __attribute__((ext_vector_type(4)));

struct Ptr5 { const float* p[5]; };

__device__ __forceinline__ unsigned short f2bf(float f) {
    unsigned u = __builtin_bit_cast(unsigned, f);
    unsigned r = (u + 0x7FFFu + ((u >> 16) & 1u)) >> 16;   // RNE
    return (unsigned short)r;
}

__device__ __forceinline__ short8 pack8(float4 a, float4 b) {
    union { unsigned short u[8]; short8 s; } o;
    o.u[0] = f2bf(a.x); o.u[1] = f2bf(a.y); o.u[2] = f2bf(a.z); o.u[3] = f2bf(a.w);
    o.u[4] = f2bf(b.x); o.u[5] = f2bf(b.y); o.u[6] = f2bf(b.z); o.u[7] = f2bf(b.w);
    return o.s;
}

// ---------------- fat prep kernel (single dispatch, no atomics-needing-init) ----
// bx [0,32):       gate GEMM: relu(x@enc^T - b) -> gate_ws + d_out gates + slot stats
// bx [32,1952):    V{g}/U{g} conv (2048 float4/block), norm partial -> vslot/uslot
// bx [1952,2336):  x -> xb bf16 cast  (+ bx==1952: zero the 48 split-K flags)

__global__ __launch_bounds__(256) void prep_k(const float* __restrict__ x,
                                              Ptr5 vp, Ptr5 up, Ptr5 ep, Ptr5 bp,
                                              unsigned short* __restrict__ vb,
                                              unsigned short* __restrict__ w2t,
                                              unsigned short* __restrict__ xb,
                                              float* __restrict__ gate_ws,
                                              float* __restrict__ outg,
                                              float* __restrict__ vslot,
                                              float* __restrict__ uslot,
                                              float* __restrict__ gslot,
                                              float* __restrict__ aslot,
                                              unsigned* __restrict__ flags) {
    const int basen[5] = {0, 4, 12, 28, 60};
    int bx = blockIdx.x;
    int tid = threadIdx.x;
    if (bx < 32) {
        // ---- gate GEMM (M=128 rows per block, N=128 cols (124 valid), K=768) ----
        __shared__ unsigned short lA[128 * 64];
        __shared__ unsigned short lB[128 * 64];
        __shared__ float sgs[128];
        __shared__ float sac;
        int wave = tid >> 6, lane = tid & 63;
        int wm = wave >> 1, wn = wave & 1;
        int lan15 = lane & 15, quad = lane >> 4;
        int sw = lan15 & 7;
        int m0 = bx * 128;
        f32x4 acc[4][4] = {};
        for (int k0 = 0; k0 < DM; k0 += 64) {
            __syncthreads();
            #pragma unroll
            for (int i = 0; i < 4; i++) {
                int gidx = i * 256 + tid;           // granule index 0..1023
                int row = gidx >> 3, kb = gidx & 7;
                int r7 = row & 7;
                int la = (row >> 3) * 512 + r7 * 64 + (kb ^ r7) * 8;
                int sidx = (m0 + row) * 192 + (k0 >> 2) + kb * 2;
                float4 a0 = ((const float4*)x)[sidx];
                float4 a1 = ((const float4*)x)[sidx + 1];
                *(short8*)(lA + la) = pack8(a0, a1);
                float4 b0 = {0.f, 0.f, 0.f, 0.f}, b1 = {0.f, 0.f, 0.f, 0.f};
                if (row < NG) {
                    int g = (row < 4) ? 0 : (row < 12) ? 1 : (row < 28) ? 2 :
                            (row < 60) ? 3 : 4;
                    int ni = row - basen[g];
                    int eidx = ni * 192 + (k0 >> 2) + kb * 2;
                    b0 = ((const float4*)ep.p[g])[eidx];
                    b1 = ((const float4*)ep.p[g])[eidx + 1];
                }
                *(short8*)(lB + la) = pack8(b0, b1);
            }
            __syncthreads();
            #pragma unroll
            for (int kk = 0; kk < 2; kk++) {
                int kb = kk * 4 + quad;
                int kel = (kb ^ sw) * 8;
                bf16x8 af[4], bfr[4];
                #pragma unroll
                for (int t = 0; t < 4; t++) {
                    short8 ra = *(const short8*)(lA + (wm * 64 + t * 16 + lan15) * 64 + kel);
                    short8 rb = *(const short8*)(lB + (wn * 64 + t * 16 + lan15) * 64 + kel);
                    af[t]  = __builtin_bit_cast(bf16x8, ra);
                    bfr[t] = __builtin_bit_cast(bf16x8, rb);
                }
                #pragma unroll
                for (int mt = 0; mt < 4; mt++)
                    #pragma unroll
                    for (int nt = 0; nt < 4; nt++)
                        acc[mt][nt] = __builtin_amdgcn_mfma_f32_16x16x32_bf16(
                            af[mt], bfr[nt], acc[mt][nt], 0, 0, 0);
            }
        }
        if (tid < 128) sgs[tid] = 0.f;
        if (tid == 0) sac = 0.f;
        __syncthreads();
        const size_t baseg[5] = {3145730ull, 3145730ull + 16384, 3145730ull + 49152,
                                 3145730ull + 114688, 3145730ull + 245760};
        float cnt = 0.f;
        #pragma unroll
        for (int nt = 0; nt < 4; nt++) {
            int col = wn * 64 + nt * 16 + lan15;
            float cs = 0.f;
            if (col < NG) {
                int g = (col < 4) ? 0 : (col < 12) ? 1 : (col < 28) ? 2 :
                        (col < 60) ? 3 : 4;
                int ni = col - basen[g];
                int w = 4 << g;
                float bv = bp.p[g][ni];
                #pragma unroll
                for (int mt = 0; mt < 4; mt++) {
                    int r0 = m0 + wm * 64 + mt * 16 + quad * 4;
                    #pragma unroll
                    for (int rg = 0; rg < 4; rg++) {
                        float pre = acc[mt][nt][rg] - bv;
                        float gt = pre > 0.f ? pre : 0.f;
                        gate_ws[(size_t)(r0 + rg) * NG + col] = gt;
                        outg[baseg[g] + (size_t)(r0 + rg) * w + ni] = gt;
                        cs += gt;
                        if (pre > 0.f) cnt += 1.f;
                    }
                }
                cs += __shfl_xor(cs, 16);
                cs += __shfl_xor(cs, 32);
                if (quad == 0) atomicAdd(&sgs[col], cs);
            }
        }
        #pragma unroll
        for (int off = 32; off > 0; off >>= 1) cnt += __shfl_xor(cnt, off);
        if (lane == 0) atomicAdd(&sac, cnt);
        __syncthreads();
        if (tid < NG) gslot[bx * NG + tid] = sgs[tid];
        if (tid == 0) aslot[bx] = sac;
    } else if (bx < 1952) {
        // ---- streaming V/U conversion + norm slots ----
        __shared__ float swave[4];
        int cb = bx - 32;
        int isV = cb < 960;
        int wb = isV ? cb : cb - 960;       // 0..959
        int g = wb / 192;
        int within = wb - g * 192;
        const float* src = isV ? vp.p[g] : up.p[g];
        int r = 512 >> g, lr = 9 - g;
        float ss = 0.f;
        #pragma unroll
        for (int i = 0; i < 8; i++) {
            int j = within * 2048 + i * 256 + tid;
            float4 v = ((const float4*)src)[j];
            ss += v.x*v.x + v.y*v.y + v.z*v.z + v.w*v.w;
            ushort4 o;
            o.x = f2bf(v.x); o.y = f2bf(v.y); o.z = f2bf(v.z); o.w = f2bf(v.w);
            if (isV) {
                ((ushort4*)vb)[(size_t)(g * 192 + within) * 2048 + i * 256 + tid] = o;
            } else {
                int idx = j * 4;
                int rr = idx & (r - 1);
                int t2 = idx >> lr;
                int d  = t2 % DM;
                int n  = t2 / DM;
                size_t dst = (size_t)d * LTOT + (size_t)(g << 11) + (size_t)n * r + rr;
                *(ushort4*)(w2t + dst) = o;
            }
        }
        #pragma unroll
        for (int off = 32; off > 0; off >>= 1) ss += __shfl_down(ss, off);
        if ((tid & 63) == 0) swave[tid >> 6] = ss;
        __syncthreads();
        if (tid == 0) {
            float t = (swave[0] + swave[1]) + (swave[2] + swave[3]);
            (isV ? vslot : uslot)[wb] = t;
        }
    } else {
        // ---- x -> xb (+ flag zeroing once) ----
        if (bx == 1952 && tid < 48) flags[tid] = 0u;
        int base = (bx - 1952) * 2048;
        #pragma unroll
        for (int i = 0; i < 8; i++) {
            int j = base + i * 256 + tid;
            float4 v = ((const float4*)x)[j];
            ushort4 o;
            o.x = f2bf(v.x); o.y = f2bf(v.y); o.z = f2bf(v.z); o.w = f2bf(v.w);
            ((ushort4*)xb)[j] = o;
        }
    }
}

// ---------------- GEMM1: fine-grained 3-buffer pipeline (T3+T4, 2 wg/CU) -------
// 256x128 block, k-tile=32, 8 waves of 64x64. Main loop unchanged (84us across
// two schedule variants -> not sync-bound). Epilogue transpose row stride padded
// 64 -> 80 ushorts (160B = 8 banks mod 32): quads land on disjoint bank octets,
// removing the measured 1.3M 4-way write conflicts. Reads stay 16B-aligned.
__global__ __launch_bounds__(512, 4) void gemm1_fg(const unsigned short* __restrict__ A,
                                                   const unsigned short* __restrict__ Bm,
                                                   unsigned short* __restrict__ Hg,
                                                   const float* __restrict__ gate) {
    __shared__ unsigned short lds[36864];   // A: 3*8192 ; B: 24576 + 3*4096
    const int tid = threadIdx.x;
    const int wave = tid >> 6, lane = tid & 63;
    const int wm = wave >> 1, wn = wave & 1;
    const int lan15 = lane & 15, quad = lane >> 4;
    const int swz = quad ^ ((lan15 >> 1) & 3);
    const int m0 = blockIdx.x * 256, n0 = blockIdx.y * 128;
    const unsigned short* Ab = A  + (size_t)m0 * DM;
    const unsigned short* Bb = Bm + (size_t)n0 * DM;
    const int srow = lane >> 2;
    const int sgr  = (lane & 3) ^ ((lane >> 3) & 3);
    const int rdA0 = (wm * 64 + lan15) * 32 + swz * 8;
    const int rdB0 = 24576 + (wn * 64 + lan15) * 32 + swz * 8;

#define STA(buf, koff) do { \
    __builtin_amdgcn_global_load_lds((const __attribute__((address_space(1))) void*)( \
        Ab + (size_t)(wave * 16 + srow) * DM + (koff) + sgr * 8), \
        (__attribute__((address_space(3))) void*)(lds + (buf) * 8192 + wave * 512), 16, 0, 0); \
    __builtin_amdgcn_global_load_lds((const __attribute__((address_space(1))) void*)( \
        Ab + (size_t)((wave + 8) * 16 + srow) * DM + (koff) + sgr * 8), \
        (__attribute__((address_space(3))) void*)(lds + (buf) * 8192 + (wave + 8) * 512), 16, 0, 0); \
} while (0)
#define STB(buf, koff) \
    __builtin_amdgcn_global_load_lds((const __attribute__((address_space(1))) void*)( \
        Bb + (size_t)(wave * 16 + srow) * DM + (koff) + sgr * 8), \
        (__attribute__((address_space(3))) void*)(lds + 24576 + (buf) * 4096 + wave * 512), 16, 0, 0)
#define SYNC1 do { __builtin_amdgcn_s_barrier(); \
    asm volatile("s_waitcnt lgkmcnt(0)" ::: "memory"); \
    __builtin_amdgcn_sched_barrier(0); } while (0)
#define SYNC2 do { asm volatile("" ::: "memory"); __builtin_amdgcn_s_barrier(); \
    asm volatile("" ::: "memory"); } while (0)

    f32x4 acc[4][4] = {};
    // prologue: tiles 0,1 (6 loads); wait oldest 3 = tile 0
    STA(0, 0); STB(0, 0);
    STA(1, 32); STB(1, 32);
    asm volatile("s_waitcnt vmcnt(3)" ::: "memory");
    __builtin_amdgcn_s_barrier();

    int buf = 0;
    for (int t = 0; t < 24; t++) {
        int bnext = buf + 2; if (bnext >= 3) bnext -= 3;
        bf16x8 af[4], bf[4];
        // phase A: frags mt 0,1 + all B; stage A[t+2]
        #pragma unroll
        for (int x = 0; x < 2; x++)
            af[x] = __builtin_bit_cast(bf16x8, *(const short8*)(lds + buf * 8192 + rdA0 + x * 512));
        #pragma unroll
        for (int x = 0; x < 4; x++)
            bf[x] = __builtin_bit_cast(bf16x8, *(const short8*)(lds + buf * 4096 + rdB0 + x * 512));
        if (t + 2 < 24) STA(bnext, (t + 2) * 32);
        SYNC1;
        __builtin_amdgcn_s_setprio(1);
        #pragma unroll
        for (int mt = 0; mt < 2; mt++)
            #pragma unroll
            for (int nt = 0; nt < 4; nt++)
                acc[mt][nt] = __builtin_amdgcn_mfma_f32_16x16x32_bf16(af[mt], bf[nt],
                                                                     acc[mt][nt], 0, 0, 0);
        __builtin_amdgcn_s_setprio(0);
        SYNC2;
        // phase B: frags mt 2,3; stage B[t+2]; counted vmcnt
        #pragma unroll
        for (int x = 0; x < 2; x++)
            af[2 + x] = __builtin_bit_cast(bf16x8, *(const short8*)(lds + buf * 8192 + rdA0 + (2 + x) * 512));
        if (t + 2 < 24) STB(bnext, (t + 2) * 32);
        SYNC1;
        __builtin_amdgcn_s_setprio(1);
        #pragma unroll
        for (int mt = 2; mt < 4; mt++)
            #pragma unroll
            for (int nt = 0; nt < 4; nt++)
                acc[mt][nt] = __builtin_amdgcn_mfma_f32_16x16x32_bf16(af[mt], bf[nt],
                                                                     acc[mt][nt], 0, 0, 0);
        __builtin_amdgcn_s_setprio(0);
        if (t >= 22) { asm volatile("s_waitcnt vmcnt(0)" ::: "memory"); }
        else         { asm volatile("s_waitcnt vmcnt(3)" ::: "memory"); }
        SYNC2;
        buf = (buf == 2) ? 0 : buf + 1;
    }
#undef STA
#undef STB
#undef SYNC1
#undef SYNC2

    // epilogue: gate multiply + bf16 + LDS transpose -> Hg[row][l] short8 stores
    // row stride 80 ushorts (padded): write banks disjoint across quads.
    const int basen[5] = {0, 4, 12, 28, 60};
    #pragma unroll
    for (int mf = 0; mf < 4; mf++) {
        #pragma unroll
        for (int nf = 0; nf < 4; nf++) {
            int col = n0 + wn * 64 + nf * 16 + lan15;
            int g = col >> 11;
            int ngl = basen[g] + ((col & 2047) >> (9 - g));
            #pragma unroll
            for (int rg = 0; rg < 4; rg++) {
                int grow = m0 + wm * 64 + mf * 16 + quad * 4 + rg;
                float gv = gate[(size_t)grow * NG + ngl];
                lds[wave * 1280 + (quad * 4 + rg) * 80 + nf * 16 + lan15] =
                    f2bf(acc[mf][nf][rg] * gv);
            }
        }
        asm volatile("s_waitcnt lgkmcnt(0)" ::: "memory");
        __builtin_amdgcn_s_barrier();
        #pragma unroll
        for (int it = 0; it < 2; it++) {
            int f = it * 512 + tid;
            int R = f >> 4;             // 0..63: block-row within this mf step
            int u = f & 15;             // col granule 0..15
            int strip = (R >> 4) * 2 + (u >> 3);
            short8 v = *(const short8*)(lds + strip * 1280 + (R & 15) * 80 + (u & 7) * 8);
            int grow = m0 + (R >> 4) * 64 + mf * 16 + (R & 15);
            *(short8*)(Hg + (size_t)grow * LTOT + n0 + u * 8) = v;
        }
        asm volatile("s_waitcnt lgkmcnt(0)" ::: "memory");
        __builtin_amdgcn_s_barrier();
    }
}

// ---------------- GEMM2: 8-phase 256x256 template + fused split-K closer -------
// Proven r5 schedule. New: after the partial store, each block fences and bumps
// a per-(x,y)-tile flag; the 5th arrival (closer) re-reads the 5 L3-hot partial
// slices and writes `out` directly — reduce_k dispatch eliminated. Tile (0,0)'s
// closer also computes the fused sparsity/active stats. Device-scope atomics +
// threadfence per Guideline 16; no spinning (closer-only work).
__global__ __launch_bounds__(512, 1) void gemm2_nt(const unsigned short* __restrict__ A,
                                                   const unsigned short* __restrict__ Bm,
                                                   float* __restrict__ P,
                                                   float* __restrict__ Out,
                                                   unsigned* __restrict__ flags,
                                                   const float* __restrict__ vslot,
                                                   const float* __restrict__ uslot,
                                                   const float* __restrict__ gslot,
                                                   const float* __restrict__ aslot,
                                                   float* __restrict__ o2) {
    __shared__ unsigned short lds[65536];   // A: [0,32768) ; B: [32768,65536)
    const int tid = threadIdx.x;
    const int wave = tid >> 6, lane = tid & 63;
    const int wm = wave >> 2, wn = wave & 3;
    const int lan15 = lane & 15, quad = lane >> 4;
    const int swz = quad ^ ((lan15 >> 1) & 3);
    const int m0 = blockIdx.x * 256, n0 = blockIdx.y * 256;
    const unsigned short* Ab = A  + (size_t)m0 * LTOT + blockIdx.z * 2048;
    const unsigned short* Bb = Bm + (size_t)n0 * LTOT + blockIdx.z * 2048;
    const int srow = lane >> 2;
    const int sgr  = (lane & 3) ^ ((lane >> 3) & 3);
    const int rdA = (wm * 128 + lan15) * 32 + swz * 8;
    const int rdB = 32768 + (wn * 64 + lan15) * 32 + swz * 8;

#define STG(base_us, gb, koff) do { \
    const unsigned short* _s0 = (gb) + (size_t)(wave * 16 + srow) * LTOT + (koff) + sgr * 8; \
    const unsigned short* _s1 = (gb) + (size_t)((wave + 8) * 16 + srow) * LTOT + (koff) + sgr * 8; \
    __builtin_amdgcn_global_load_lds((const __attribute__((address_space(1))) void*)_s0, \
        (__attribute__((address_space(3))) void*)(lds + (base_us) + wave * 512), 16, 0, 0); \
    __builtin_amdgcn_global_load_lds((const __attribute__((address_space(1))) void*)_s1, \
        (__attribute__((address_space(3))) void*)(lds + (base_us) + (wave + 8) * 512), 16, 0, 0); \
} while (0)
#define STGA(buf, kh, koff) STG(((buf) * 2 + (kh)) * 8192, Ab, koff)
#define STGB(buf, kh, koff) STG(32768 + ((buf) * 2 + (kh)) * 8192, Bb, koff)

#define RDA(msub, bufkg) { \
    _Pragma("unroll") for (int t = 0; t < 4; t++) \
        af[t] = __builtin_bit_cast(bf16x8, \
            *(const short8*)(lds + (bufkg) * 8192 + rdA + ((msub) * 64 + t * 16) * 32)); }
#define RDB(bufkg) { \
    _Pragma("unroll") for (int t = 0; t < 4; t++) \
        bf[t] = __builtin_bit_cast(bf16x8, \
            *(const short8*)(lds + 32768 + (bufkg) * 8192 + rdB - 32768 + t * 512)); }
#define SYNC1 do { __builtin_amdgcn_s_barrier(); \
    asm volatile("s_waitcnt lgkmcnt(0)" ::: "memory"); \
    __builtin_amdgcn_sched_barrier(0); } while (0)
#define MM(msub) do { __builtin_amdgcn_s_setprio(1); \
    _Pragma("unroll") for (int mt = 0; mt < 4; mt++) \
        _Pragma("unroll") for (int nf = 0; nf < 4; nf++) \
            acc[(msub) * 4 + mt][nf] = __builtin_amdgcn_mfma_f32_16x16x32_bf16( \
                af[mt], bf[nf], acc[(msub) * 4 + mt][nf], 0, 0, 0); \
    __builtin_amdgcn_s_setprio(0); } while (0)
#define SYNC2 do { asm volatile("" ::: "memory"); __builtin_amdgcn_s_barrier(); \
    asm volatile("" ::: "memory"); } while (0)

    f32x4 acc[8][4] = {};
    // prologue: 7 half-tiles, oldest-first; vmcnt(10) leaves 5 halves in flight
    STGA(0, 0, 0);  STGB(0, 0, 0);
    STGA(0, 1, 32); STGB(0, 1, 32);
    STGA(1, 0, 64); STGB(1, 0, 64);
    STGB(1, 1, 96);
    asm volatile("s_waitcnt vmcnt(10)" ::: "memory");
    __builtin_amdgcn_s_barrier();

    for (int i = 0; i < 32; i++) {
        const int buf = i & 1;
        bf16x8 af[4], bf[4];
        // phase 1: msub0, kg0; stage A[buf^1][k1] for tile i+1
        RDA(0, buf * 2 + 0); RDB(buf * 2 + 0);
        if (i + 1 < 32) STGA(buf ^ 1, 1, (i + 1) * 64 + 32);
        SYNC1; MM(0); SYNC2;
        // phase 2: msub1, kg0; stage B[buf][k0] for tile i+2; counted vmcnt
        RDA(1, buf * 2 + 0);
        if (i + 2 < 32) STGB(buf, 0, (i + 2) * 64);
        SYNC1; MM(1);
        if (i == 31) { asm volatile("s_waitcnt vmcnt(0)" ::: "memory"); }
        else         { asm volatile("s_waitcnt vmcnt(6)" ::: "memory"); }
        SYNC2;
        // phase 3: msub0, kg1; stage A[buf][k0] for tile i+2
        RDA(0, buf * 2 + 1); RDB(buf * 2 + 1);
        if (i + 2 < 32) STGA(buf, 0, (i + 2) * 64);
        SYNC1; MM(0); SYNC2;
        // phase 4: msub1, kg1; stage B[buf][k1] for tile i+2
        RDA(1, buf * 2 + 1);
        if (i + 2 < 32) STGB(buf, 1, (i + 2) * 64 + 32);
        SYNC1; MM(1); SYNC2;
    }
    asm volatile("s_waitcnt vmcnt(0)" ::: "memory");
#undef STG
#undef STGA
#undef STGB
#undef RDA
#undef RDB
#undef SYNC1
#undef SYNC2
#undef MM

    float* Pz = P + (size_t)blockIdx.z * ((size_t)BATCH * DM);
    #pragma unroll
    for (int mf = 0; mf < 8; mf++) {
        #pragma unroll
        for (int rg = 0; rg < 4; rg++) {
            int row = m0 + wm * 128 + mf * 16 + quad * 4 + rg;
            float* pr = Pz + (size_t)row * DM + n0 + wn * 64 + lan15;
            #pragma unroll
            for (int nf = 0; nf < 4; nf++)
                pr[nf * 16] = acc[mf][nf][rg];
        }
    }

    // ---- fused split-K closer ----
    __threadfence();
    __syncthreads();
    unsigned* uf = (unsigned*)lds;
    if (tid == 0) uf[0] = atomicAdd(&flags[blockIdx.x * 3 + blockIdx.y], 1u);
    __syncthreads();
    unsigned arr = uf[0];
    if (arr == 4u) {
        __threadfence();
        const float4* P4 = (const float4*)P;
        float4* O4 = (float4*)Out;
        const size_t zs = (size_t)BATCH * DM / 4;
        for (int j = 0; j < 32; j++) {
            int i = j * 512 + tid;              // 0..16383 float4 within tile
            int row = i >> 6, c4 = i & 63;
            size_t g4 = (size_t)(m0 + row) * 192 + (n0 >> 2) + c4;
            float4 a0 = P4[g4], a1 = P4[g4 + zs], a2 = P4[g4 + 2 * zs];
            float4 a3 = P4[g4 + 3 * zs], a4 = P4[g4 + 4 * zs];
            float4 s;
            s.x = ((a0.x + a1.x) + (a2.x + a3.x)) + a4.x;
            s.y = ((a0.y + a1.y) + (a2.y + a3.y)) + a4.y;
            s.z = ((a0.z + a1.z) + (a2.z + a3.z)) + a4.z;
            s.w = ((a0.w + a1.w) + (a2.w + a3.w)) + a4.w;
            O4[g4] = s;
        }
        if (blockIdx.x == 0 && blockIdx.y == 0) {
            float* sh = (float*)lds + 32;
            const int basen[5] = {0, 4, 12, 28, 60};
            int t = tid;
            if (t < 128) {
                float v = 0.f;
                if (t < NG) {
                    int g = (t < 4) ? 0 : (t < 12) ? 1 : (t < 28) ? 2 : (t < 60) ? 3 : 4;
                    int nloc = t - basen[g];
                    int bpseg = 48 >> g;
                    float vs = 0.f, us = 0.f;
                    int base = g * 192 + nloc * bpseg;
                    for (int j = 0; j < bpseg; j++) { vs += vslot[base + j]; us += uslot[base + j]; }
                    float gs = 0.f;
                    for (int bb = 0; bb < 32; bb++) gs += gslot[bb * NG + t];
                    float rr = (float)(512 >> g);
                    float mean = gs * (1.0f / BATCH);
                    float frob = sqrtf(us * vs) / sqrtf(768.0f * rr);
                    v = tanhf(mean) * frob;
                }
                sh[t] = v;
            }
            if (t == 128) {
                float asum = 0.f;
                for (int bb = 0; bb < 32; bb++) asum += aslot[bb];
                o2[1] = asum * (1.0f / BATCH);
            }
            __syncthreads();
            for (int s2 = 64; s2 > 0; s2 >>= 1) {
                if (tid < s2) sh[tid] += sh[tid + s2];
                __syncthreads();
            }
            if (tid == 0) o2[0] = sh[0];
        }
    }
}

// ---------------- launcher ----------------
// Workspace: w2t (15.73) | slots (~0.03) | flags | Hg (83.9) | partial 5*12.58
// xb/vb/gate_ws ALIASED into the partial region (dead after gemm1; partial
// written only by gemm2, stream-ordered after). Single-chunk (CB == BATCH).
// reduce_k eliminated: split-K reduction + stats fused into gemm2's closer.

extern "C" void kernel_launch(void* const* d_in, const int* in_sizes, int n_in,
                              void* d_out, int out_size, void* d_ws, size_t ws_size,
                              hipStream_t stream) {
    const float* x = (const float*)d_in[0];
    Ptr5 vp, up, ep, bp;
    for (int g = 0; g < 5; g++) {
        vp.p[g] = (const float*)d_in[1 + 4 * g];
        up.p[g] = (const float*)d_in[2 + 4 * g];
        ep.p[g] = (const float*)d_in[3 + 4 * g];
        bp.p[g] = (const float*)d_in[4 + 4 * g];
    }
    float* out = (float*)d_out;
    char* ws = (char*)d_ws;
    size_t off = 0;
    unsigned short* w2t  = (unsigned short*)(ws + off); off += (size_t)LTOT * DM * 2;
    float* vslot         = (float*)(ws + off);          off += 960 * 4;
    float* uslot         = (float*)(ws + off);          off += 960 * 4;
    float* gslot         = (float*)(ws + off);          off += 32 * NG * 4;
    float* aslot         = (float*)(ws + off);          off += 32 * 4 + 256;
    unsigned* flags      = (unsigned*)(ws + off);       off += 256;
    unsigned short* Hg   = (unsigned short*)(ws + off); off += (size_t)BATCH * LTOT * 2;
    float* partial       = (float*)(ws + off);          off += 5ull * BATCH * DM * 4;
    // aliases inside the partial region (24.1 MB used of 62.9):
    unsigned short* xb      = (unsigned short*)partial;
    unsigned short* vb      = (unsigned short*)((char*)partial + (size_t)BATCH * DM * 2);
    float* gate_ws          = (float*)((char*)partial + (size_t)BATCH * DM * 2
                                                      + (size_t)LTOT * DM * 2);

    prep_k<<<dim3(2336), 256, 0, stream>>>(
        x, vp, up, ep, bp, vb, w2t, xb, gate_ws, out,
        vslot, uslot, gslot, aslot, flags);

    // GEMM1: Hg = gate .* (x @ V^T)  (M=4096, N=10240, K=768), fine-grained 3-buf
    gemm1_fg<<<dim3(BATCH / 256, LTOT / 128, 1), 512, 0, stream>>>(
        xb, vb, Hg, gate_ws);
    // GEMM2: out = Hg @ W2  (M=4096, N=768, K=10240), split-K=5, fused closer
    gemm2_nt<<<dim3(BATCH / 256, DM / 256, 5), 512, 0, stream>>>(
        Hg, w2t, partial, out, flags, vslot, uslot, gslot, aslot,
        out + (size_t)BATCH * DM);
}

// Round 8
// 332.618 us; speedup vs baseline: 1.2226x; 1.2226x over previous
//
#include <hip/hip_runtime.h>

#define BATCH 4096
#define DM 768
#define LTOT 10240
#define NG 124

typedef __bf16 bf16x8 __attribute__((ext_vector_type(8)));
typedef short short8 __attribute__((ext_vector_type(8)));
typedef float f32x4 __attribute__((ext_vector_type(4)));

struct Ptr5 { const float* p[5]; };

__device__ __forceinline__ unsigned short f2bf(float f) {
    unsigned u = __builtin_bit_cast(unsigned, f);
    unsigned r = (u + 0x7FFFu + ((u >> 16) & 1u)) >> 16;   // RNE
    return (unsigned short)r;
}

__device__ __forceinline__ short8 pack8(float4 a, float4 b) {
    union { unsigned short u[8]; short8 s; } o;
    o.u[0] = f2bf(a.x); o.u[1] = f2bf(a.y); o.u[2] = f2bf(a.z); o.u[3] = f2bf(a.w);
    o.u[4] = f2bf(b.x); o.u[5] = f2bf(b.y); o.u[6] = f2bf(b.z); o.u[7] = f2bf(b.w);
    return o.s;
}

// ---------------- fat prep kernel (single dispatch, no atomics-needing-init) ----
// bx [0,32):       gate GEMM: relu(x@enc^T - b) -> gate_ws + d_out gates + slot stats
// bx [32,1952):    V{g}/U{g} conv (2048 float4/block), norm partial -> vslot/uslot
// bx [1952,2336):  x -> xb bf16 cast

__global__ __launch_bounds__(256) void prep_k(const float* __restrict__ x,
                                              Ptr5 vp, Ptr5 up, Ptr5 ep, Ptr5 bp,
                                              unsigned short* __restrict__ vb,
                                              unsigned short* __restrict__ w2t,
                                              unsigned short* __restrict__ xb,
                                              float* __restrict__ gate_ws,
                                              float* __restrict__ outg,
                                              float* __restrict__ vslot,
                                              float* __restrict__ uslot,
                                              float* __restrict__ gslot,
                                              float* __restrict__ aslot) {
    const int basen[5] = {0, 4, 12, 28, 60};
    int bx = blockIdx.x;
    int tid = threadIdx.x;
    if (bx < 32) {
        // ---- gate GEMM (M=128 rows per block, N=128 cols (124 valid), K=768) ----
        __shared__ unsigned short lA[128 * 64];
        __shared__ unsigned short lB[128 * 64];
        __shared__ float sgs[128];
        __shared__ float sac;
        int wave = tid >> 6, lane = tid & 63;
        int wm = wave >> 1, wn = wave & 1;
        int lan15 = lane & 15, quad = lane >> 4;
        int sw = lan15 & 7;
        int m0 = bx * 128;
        f32x4 acc[4][4] = {};
        for (int k0 = 0; k0 < DM; k0 += 64) {
            __syncthreads();
            #pragma unroll
            for (int i = 0; i < 4; i++) {
                int gidx = i * 256 + tid;           // granule index 0..1023
                int row = gidx >> 3, kb = gidx & 7;
                int r7 = row & 7;
                int la = (row >> 3) * 512 + r7 * 64 + (kb ^ r7) * 8;
                int sidx = (m0 + row) * 192 + (k0 >> 2) + kb * 2;
                float4 a0 = ((const float4*)x)[sidx];
                float4 a1 = ((const float4*)x)[sidx + 1];
                *(short8*)(lA + la) = pack8(a0, a1);
                float4 b0 = {0.f, 0.f, 0.f, 0.f}, b1 = {0.f, 0.f, 0.f, 0.f};
                if (row < NG) {
                    int g = (row < 4) ? 0 : (row < 12) ? 1 : (row < 28) ? 2 :
                            (row < 60) ? 3 : 4;
                    int ni = row - basen[g];
                    int eidx = ni * 192 + (k0 >> 2) + kb * 2;
                    b0 = ((const float4*)ep.p[g])[eidx];
                    b1 = ((const float4*)ep.p[g])[eidx + 1];
                }
                *(short8*)(lB + la) = pack8(b0, b1);
            }
            __syncthreads();
            #pragma unroll
            for (int kk = 0; kk < 2; kk++) {
                int kb = kk * 4 + quad;
                int kel = (kb ^ sw) * 8;
                bf16x8 af[4], bfr[4];
                #pragma unroll
                for (int t = 0; t < 4; t++) {
                    short8 ra = *(const short8*)(lA + (wm * 64 + t * 16 + lan15) * 64 + kel);
                    short8 rb = *(const short8*)(lB + (wn * 64 + t * 16 + lan15) * 64 + kel);
                    af[t]  = __builtin_bit_cast(bf16x8, ra);
                    bfr[t] = __builtin_bit_cast(bf16x8, rb);
                }
                #pragma unroll
                for (int mt = 0; mt < 4; mt++)
                    #pragma unroll
                    for (int nt = 0; nt < 4; nt++)
                        acc[mt][nt] = __builtin_amdgcn_mfma_f32_16x16x32_bf16(
                            af[mt], bfr[nt], acc[mt][nt], 0, 0, 0);
            }
        }
        if (tid < 128) sgs[tid] = 0.f;
        if (tid == 0) sac = 0.f;
        __syncthreads();
        const size_t baseg[5] = {3145730ull, 3145730ull + 16384, 3145730ull + 49152,
                                 3145730ull + 114688, 3145730ull + 245760};
        float cnt = 0.f;
        #pragma unroll
        for (int nt = 0; nt < 4; nt++) {
            int col = wn * 64 + nt * 16 + lan15;
            float cs = 0.f;
            if (col < NG) {
                int g = (col < 4) ? 0 : (col < 12) ? 1 : (col < 28) ? 2 :
                        (col < 60) ? 3 : 4;
                int ni = col - basen[g];
                int w = 4 << g;
                float bv = bp.p[g][ni];
                #pragma unroll
                for (int mt = 0; mt < 4; mt++) {
                    int r0 = m0 + wm * 64 + mt * 16 + quad * 4;
                    #pragma unroll
                    for (int rg = 0; rg < 4; rg++) {
                        float pre = acc[mt][nt][rg] - bv;
                        float gt = pre > 0.f ? pre : 0.f;
                        gate_ws[(size_t)(r0 + rg) * NG + col] = gt;
                        outg[baseg[g] + (size_t)(r0 + rg) * w + ni] = gt;
                        cs += gt;
                        if (pre > 0.f) cnt += 1.f;
                    }
                }
                cs += __shfl_xor(cs, 16);
                cs += __shfl_xor(cs, 32);
                if (quad == 0) atomicAdd(&sgs[col], cs);
            }
        }
        #pragma unroll
        for (int off = 32; off > 0; off >>= 1) cnt += __shfl_xor(cnt, off);
        if (lane == 0) atomicAdd(&sac, cnt);
        __syncthreads();
        if (tid < NG) gslot[bx * NG + tid] = sgs[tid];
        if (tid == 0) aslot[bx] = sac;
    } else if (bx < 1952) {
        // ---- streaming V/U conversion + norm slots ----
        __shared__ float swave[4];
        int cb = bx - 32;
        int isV = cb < 960;
        int wb = isV ? cb : cb - 960;       // 0..959
        int g = wb / 192;
        int within = wb - g * 192;
        const float* src = isV ? vp.p[g] : up.p[g];
        int r = 512 >> g, lr = 9 - g;
        float ss = 0.f;
        #pragma unroll
        for (int i = 0; i < 8; i++) {
            int j = within * 2048 + i * 256 + tid;
            float4 v = ((const float4*)src)[j];
            ss += v.x*v.x + v.y*v.y + v.z*v.z + v.w*v.w;
            ushort4 o;
            o.x = f2bf(v.x); o.y = f2bf(v.y); o.z = f2bf(v.z); o.w = f2bf(v.w);
            if (isV) {
                ((ushort4*)vb)[(size_t)(g * 192 + within) * 2048 + i * 256 + tid] = o;
            } else {
                int idx = j * 4;
                int rr = idx & (r - 1);
                int t2 = idx >> lr;
                int d  = t2 % DM;
                int n  = t2 / DM;
                size_t dst = (size_t)d * LTOT + (size_t)(g << 11) + (size_t)n * r + rr;
                *(ushort4*)(w2t + dst) = o;
            }
        }
        #pragma unroll
        for (int off = 32; off > 0; off >>= 1) ss += __shfl_down(ss, off);
        if ((tid & 63) == 0) swave[tid >> 6] = ss;
        __syncthreads();
        if (tid == 0) {
            float t = (swave[0] + swave[1]) + (swave[2] + swave[3]);
            (isV ? vslot : uslot)[wb] = t;
        }
    } else {
        // ---- x -> xb ----
        int base = (bx - 1952) * 2048;
        #pragma unroll
        for (int i = 0; i < 8; i++) {
            int j = base + i * 256 + tid;
            float4 v = ((const float4*)x)[j];
            ushort4 o;
            o.x = f2bf(v.x); o.y = f2bf(v.y); o.z = f2bf(v.z); o.w = f2bf(v.w);
            ((ushort4*)xb)[j] = o;
        }
    }
}

// ---------------- shared staging helper (XOR-swizzled async global->LDS) -------
template <int ROWS, int NT>
__device__ __forceinline__ void stage(const unsigned short* __restrict__ src, int ld,
                                      unsigned short* lds, int wv, int lane) {
    int rsub = lane >> 3;
    int colb = ((lane ^ rsub) & 7) * 8;
    #pragma unroll
    for (int i = 0; i < ROWS * 8 / NT; i++) {
        int c = i * (NT / 64) + wv;
        const unsigned short* gp = src + (size_t)(c * 8 + rsub) * ld + colb;
        __builtin_amdgcn_global_load_lds((const __attribute__((address_space(1))) void*)gp,
                                         (__attribute__((address_space(3))) void*)(lds + c * 512),
                                         16, 0, 0);
    }
}

// ---------------- GEMM1: 16x16x32 MFMA, gate + bf16 Hg LDS-transposed epilogue --
// NEW (T1): XCD-aware block swizzle. gemm1 is pinned at 84us across 3 schedule
// variants -> not sync/LDS-bound. Theory: ~750 MB of A/B panel re-reads go
// through L3 because the m-fast linear grid puts same-B blocks on all 8 XCDs
// (and 32%8==0 stacks same-A blocks on ONE XCD, replicating B into every L2).
// Swizzle gives XCD k the contiguous chunk virt=[k*160,(k+1)*160): all 32 m x
// 5 n-panels -> its 5 B panels (1.97 MB) stay L2-resident; L3 traffic ~750 ->
// ~280 MB. Bijective (1280 blocks % 8 == 0). Falsifier: >=80us kills theory.
template <int BM, int BN, int NT>
__global__ __launch_bounds__(NT) void gemm_nt(const unsigned short* __restrict__ A,
                                              const unsigned short* __restrict__ Bm,
                                              int Kblk, int lda, int ldb,
                                              void* __restrict__ Cout,
                                              const float* __restrict__ gate, int ldc) {
    __shared__ unsigned short lA[BM * 64];
    __shared__ unsigned short lB[BN * 64];
    int tid = threadIdx.x, wave = tid >> 6, lane = tid & 63;
    constexpr int WN = BN / 64;
    int wm = wave / WN, wn = wave % WN;
    // XCD swizzle: flat dispatch id -> per-XCD contiguous (m-fast, n-chunked)
    int flat = blockIdx.x + blockIdx.y * gridDim.x;
    int per = (gridDim.x * gridDim.y) >> 3;
    int virt = (flat & 7) * per + (flat >> 3);
    int bxm = virt % gridDim.x, byn = virt / gridDim.x;
    int m0 = bxm * BM, n0 = byn * BN;
    A  += (size_t)m0 * lda;
    Bm += (size_t)n0 * ldb;
    f32x4 acc[4][4] = {};
    int lan15 = lane & 15, quad = lane >> 4;
    int sw = lan15 & 7;

    for (int k0 = 0; k0 < Kblk; k0 += 64) {
        stage<BM, NT>(A + k0, lda, lA, wave, lane);
        stage<BN, NT>(Bm + k0, ldb, lB, wave, lane);
        __syncthreads();
        #pragma unroll
        for (int kk = 0; kk < 2; kk++) {
            int kb = kk * 4 + quad;
            int kel = (kb ^ sw) * 8;
            bf16x8 af[4], bfr[4];
            #pragma unroll
            for (int t = 0; t < 4; t++) {
                short8 ra = *(const short8*)(lA + (size_t)(wm * 64 + t * 16 + lan15) * 64 + kel);
                short8 rb = *(const short8*)(lB + (size_t)(wn * 64 + t * 16 + lan15) * 64 + kel);
                af[t]  = __builtin_bit_cast(bf16x8, ra);
                bfr[t] = __builtin_bit_cast(bf16x8, rb);
            }
            #pragma unroll
            for (int mt = 0; mt < 4; mt++)
                #pragma unroll
                for (int nt = 0; nt < 4; nt++)
                    acc[mt][nt] = __builtin_amdgcn_mfma_f32_16x16x32_bf16(af[mt], bfr[nt],
                                                                          acc[mt][nt], 0, 0, 0);
        }
        __syncthreads();
    }

    const int basen[5] = {0, 4, 12, 28, 60};
    unsigned short* H = (unsigned short*)Cout;
    #pragma unroll
    for (int mt = 0; mt < 4; mt++) {
        __syncthreads();
        #pragma unroll
        for (int nt = 0; nt < 4; nt++) {
            int col = n0 + wn * 64 + nt * 16 + lan15;
            int g = col >> 11;
            int ngl = basen[g] + ((col & 2047) >> (9 - g));
            #pragma unroll
            for (int rg = 0; rg < 4; rg++) {
                int grow = m0 + wm * 64 + mt * 16 + quad * 4 + rg;
                float gv = gate[(size_t)grow * NG + ngl];
                lA[wave * 1024 + (quad * 4 + rg) * 64 + nt * 16 + lan15] =
                    f2bf(acc[mt][nt][rg] * gv);
            }
        }
        __syncthreads();
        #pragma unroll
        for (int i = 0; i < 2; i++) {
            int f = i * NT + tid;
            int R = f >> 5;
            int u = f & 31;
            int wv2 = ((R >> 4) << 2) + (u >> 3);
            short8 vread = *(const short8*)(lA + wv2 * 1024 + (R & 15) * 64 + (u & 7) * 8);
            int grow = m0 + (R >> 4) * 64 + mt * 16 + (R & 15);
            *(short8*)(H + (size_t)grow * ldc + n0 + u * 8) = vread;
        }
    }
}

// ---------------- GEMM2: 8-phase 256x256 template (T2+T3+T4+T5) ----------------
// r5-proven schedule (replaced the 80us 2-barrier loop). Closer fusion REVERTED
// (r7: 48-block tail reduction on 19% of chip cost +85us). Kept: i==31 tail
// vmcnt(0) race fix.
__global__ __launch_bounds__(512, 1) void gemm2_nt(const unsigned short* __restrict__ A,
                                                   const unsigned short* __restrict__ Bm,
                                                   float* __restrict__ P) {
    __shared__ unsigned short lds[65536];   // A: [0,32768) ; B: [32768,65536)
    const int tid = threadIdx.x;
    const int wave = tid >> 6, lane = tid & 63;
    const int wm = wave >> 2, wn = wave & 3;
    const int lan15 = lane & 15, quad = lane >> 4;
    const int swz = quad ^ ((lan15 >> 1) & 3);
    const int m0 = blockIdx.x * 256, n0 = blockIdx.y * 256;
    const unsigned short* Ab = A  + (size_t)m0 * LTOT + blockIdx.z * 2048;
    const unsigned short* Bb = Bm + (size_t)n0 * LTOT + blockIdx.z * 2048;
    const int srow = lane >> 2;
    const int sgr  = (lane & 3) ^ ((lane >> 3) & 3);
    const int rdA = (wm * 128 + lan15) * 32 + swz * 8;
    const int rdB = 32768 + (wn * 64 + lan15) * 32 + swz * 8;

#define STG(base_us, gb, koff) do { \
    const unsigned short* _s0 = (gb) + (size_t)(wave * 16 + srow) * LTOT + (koff) + sgr * 8; \
    const unsigned short* _s1 = (gb) + (size_t)((wave + 8) * 16 + srow) * LTOT + (koff) + sgr * 8; \
    __builtin_amdgcn_global_load_lds((const __attribute__((address_space(1))) void*)_s0, \
        (__attribute__((address_space(3))) void*)(lds + (base_us) + wave * 512), 16, 0, 0); \
    __builtin_amdgcn_global_load_lds((const __attribute__((address_space(1))) void*)_s1, \
        (__attribute__((address_space(3))) void*)(lds + (base_us) + (wave + 8) * 512), 16, 0, 0); \
} while (0)
#define STGA(buf, kh, koff) STG(((buf) * 2 + (kh)) * 8192, Ab, koff)
#define STGB(buf, kh, koff) STG(32768 + ((buf) * 2 + (kh)) * 8192, Bb, koff)

#define RDA(msub, bufkg) { \
    _Pragma("unroll") for (int t = 0; t < 4; t++) \
        af[t] = __builtin_bit_cast(bf16x8, \
            *(const short8*)(lds + (bufkg) * 8192 + rdA + ((msub) * 64 + t * 16) * 32)); }
#define RDB(bufkg) { \
    _Pragma("unroll") for (int t = 0; t < 4; t++) \
        bf[t] = __builtin_bit_cast(bf16x8, \
            *(const short8*)(lds + 32768 + (bufkg) * 8192 + rdB - 32768 + t * 512)); }
#define SYNC1 do { __builtin_amdgcn_s_barrier(); \
    asm volatile("s_waitcnt lgkmcnt(0)" ::: "memory"); \
    __builtin_amdgcn_sched_barrier(0); } while (0)
#define MM(msub) do { __builtin_amdgcn_s_setprio(1); \
    _Pragma("unroll") for (int mt = 0; mt < 4; mt++) \
        _Pragma("unroll") for (int nf = 0; nf < 4; nf++) \
            acc[(msub) * 4 + mt][nf] = __builtin_amdgcn_mfma_f32_16x16x32_bf16( \
                af[mt], bf[nf], acc[(msub) * 4 + mt][nf], 0, 0, 0); \
    __builtin_amdgcn_s_setprio(0); } while (0)
#define SYNC2 do { asm volatile("" ::: "memory"); __builtin_amdgcn_s_barrier(); \
    asm volatile("" ::: "memory"); } while (0)

    f32x4 acc[8][4] = {};
    // prologue: 7 half-tiles, oldest-first; vmcnt(10) leaves 5 halves in flight
    STGA(0, 0, 0);  STGB(0, 0, 0);
    STGA(0, 1, 32); STGB(0, 1, 32);
    STGA(1, 0, 64); STGB(1, 0, 64);
    STGB(1, 1, 96);
    asm volatile("s_waitcnt vmcnt(10)" ::: "memory");
    __builtin_amdgcn_s_barrier();

    for (int i = 0; i < 32; i++) {
        const int buf = i & 1;
        bf16x8 af[4], bf[4];
        // phase 1: msub0, kg0; stage A[buf^1][k1] for tile i+1
        RDA(0, buf * 2 + 0); RDB(buf * 2 + 0);
        if (i + 1 < 32) STGA(buf ^ 1, 1, (i + 1) * 64 + 32);
        SYNC1; MM(0); SYNC2;
        // phase 2: msub1, kg0; stage B[buf][k0] for tile i+2; counted vmcnt
        RDA(1, buf * 2 + 0);
        if (i + 2 < 32) STGB(buf, 0, (i + 2) * 64);
        SYNC1; MM(1);
        if (i == 31) { asm volatile("s_waitcnt vmcnt(0)" ::: "memory"); }
        else         { asm volatile("s_waitcnt vmcnt(6)" ::: "memory"); }
        SYNC2;
        // phase 3: msub0, kg1; stage A[buf][k0] for tile i+2
        RDA(0, buf * 2 + 1); RDB(buf * 2 + 1);
        if (i + 2 < 32) STGA(buf, 0, (i + 2) * 64);
        SYNC1; MM(0); SYNC2;
        // phase 4: msub1, kg1; stage B[buf][k1] for tile i+2
        RDA(1, buf * 2 + 1);
        if (i + 2 < 32) STGB(buf, 1, (i + 2) * 64 + 32);
        SYNC1; MM(1); SYNC2;
    }
    asm volatile("s_waitcnt vmcnt(0)" ::: "memory");
#undef STG
#undef STGA
#undef STGB
#undef RDA
#undef RDB
#undef SYNC1
#undef SYNC2
#undef MM

    float* Pz = P + (size_t)blockIdx.z * ((size_t)BATCH * DM);
    #pragma unroll
    for (int mf = 0; mf < 8; mf++) {
        #pragma unroll
        for (int rg = 0; rg < 4; rg++) {
            int row = m0 + wm * 128 + mf * 16 + quad * 4 + rg;
            float* pr = Pz + (size_t)row * DM + n0 + wn * 64 + lan15;
            #pragma unroll
            for (int nf = 0; nf < 4; nf++)
                pr[nf * 16] = acc[mf][nf][rg];
        }
    }
}

// ---------------- split-K (5-way) reduce + fused final stats (block 0) ---------
// Restored: full-chip 3072-block reduction (13us) vs r7's 48-closer tail (+85us).

__global__ __launch_bounds__(256) void reduce_k(const float4* __restrict__ P,
                                                float4* __restrict__ out, int quarter,
                                                const float* __restrict__ vslot,
                                                const float* __restrict__ uslot,
                                                const float* __restrict__ gslot,
                                                const float* __restrict__ aslot,
                                                float* __restrict__ o2) {
    int i = blockIdx.x * 256 + threadIdx.x;
    float4 a = P[i], b = P[i + quarter], c = P[i + 2 * quarter], d = P[i + 3 * quarter];
    float4 e = P[i + 4 * quarter];
    float4 o;
    o.x = ((a.x + b.x) + (c.x + d.x)) + e.x;
    o.y = ((a.y + b.y) + (c.y + d.y)) + e.y;
    o.z = ((a.z + b.z) + (c.z + d.z)) + e.z;
    o.w = ((a.w + b.w) + (c.w + d.w)) + e.w;
    out[i] = o;
    if (blockIdx.x == 0) {
        __shared__ float sh[128];
        const int basen[5] = {0, 4, 12, 28, 60};
        int t = threadIdx.x;
        if (t < 128) {
            float v = 0.f;
            if (t < NG) {
                int g = (t < 4) ? 0 : (t < 12) ? 1 : (t < 28) ? 2 : (t < 60) ? 3 : 4;
                int nloc = t - basen[g];
                int bpseg = 48 >> g;
                float vs = 0.f, us = 0.f;
                int base = g * 192 + nloc * bpseg;
                for (int j = 0; j < bpseg; j++) { vs += vslot[base + j]; us += uslot[base + j]; }
                float gs = 0.f;
                for (int bb = 0; bb < 32; bb++) gs += gslot[bb * NG + t];
                float rr = (float)(512 >> g);
                float mean = gs * (1.0f / BATCH);
                float frob = sqrtf(us * vs) / sqrtf(768.0f * rr);
                v = tanhf(mean) * frob;
            }
            sh[t] = v;
        }
        if (t == 128) {
            float asum = 0.f;
            for (int bb = 0; bb < 32; bb++) asum += aslot[bb];
            o2[1] = asum * (1.0f / BATCH);
        }
        __syncthreads();
        for (int s = 64; s > 0; s >>= 1) {
            if (threadIdx.x < s) sh[threadIdx.x] += sh[threadIdx.x + s];
            __syncthreads();
        }
        if (threadIdx.x == 0) o2[0] = sh[0];
    }
}

// ---------------- launcher ----------------
// Workspace: w2t (15.73) | slots (~0.03) | Hg (83.9) | partial 5*12.58 = 62.9
// xb/vb/gate_ws ALIASED into the partial region (dead after gemm1; partial
// written only by gemm2, stream-ordered after). Single-chunk (CB == BATCH).

extern "C" void kernel_launch(void* const* d_in, const int* in_sizes, int n_in,
                              void* d_out, int out_size, void* d_ws, size_t ws_size,
                              hipStream_t stream) {
    const float* x = (const float*)d_in[0];
    Ptr5 vp, up, ep, bp;
    for (int g = 0; g < 5; g++) {
        vp.p[g] = (const float*)d_in[1 + 4 * g];
        up.p[g] = (const float*)d_in[2 + 4 * g];
        ep.p[g] = (const float*)d_in[3 + 4 * g];
        bp.p[g] = (const float*)d_in[4 + 4 * g];
    }
    float* out = (float*)d_out;
    char* ws = (char*)d_ws;
    size_t off = 0;
    unsigned short* w2t  = (unsigned short*)(ws + off); off += (size_t)LTOT * DM * 2;
    float* vslot         = (float*)(ws + off);          off += 960 * 4;
    float* uslot         = (float*)(ws + off);          off += 960 * 4;
    float* gslot         = (float*)(ws + off);          off += 32 * NG * 4;
    float* aslot         = (float*)(ws + off);          off += 32 * 4 + 256;
    unsigned short* Hg   = (unsigned short*)(ws + off); off += (size_t)BATCH * LTOT * 2;
    float* partial       = (float*)(ws + off);          off += 5ull * BATCH * DM * 4;
    // aliases inside the partial region (24.1 MB used of 62.9):
    unsigned short* xb      = (unsigned short*)partial;
    unsigned short* vb      = (unsigned short*)((char*)partial + (size_t)BATCH * DM * 2);
    float* gate_ws          = (float*)((char*)partial + (size_t)BATCH * DM * 2
                                                      + (size_t)LTOT * DM * 2);

    prep_k<<<dim3(2336), 256, 0, stream>>>(
        x, vp, up, ep, bp, vb, w2t, xb, gate_ws, out,
        vslot, uslot, gslot, aslot);

    // GEMM1: Hg = gate .* (x @ V^T)   (M=4096, N=10240, K=768), XCD-swizzled grid
    gemm_nt<128, 256, 512><<<dim3(BATCH / 128, LTOT / 256, 1), 512, 0, stream>>>(
        xb, vb, DM, DM, DM, (void*)Hg, gate_ws, LTOT);
    // GEMM2: out = Hg @ W2   (M=4096, N=768, K=10240), split-K=5, 8-phase 256^2
    gemm2_nt<<<dim3(BATCH / 256, DM / 256, 5), 512, 0, stream>>>(Hg, w2t, partial);
    // 5-way reduce + fused final stats (block 0)
    reduce_k<<<dim3(BATCH * DM / 4 / 256), 256, 0, stream>>>(
        (const float4*)partial, (float4*)out, BATCH * DM / 4,
        vslot, uslot, gslot, aslot, out + (size_t)BATCH * DM);
}